// Round 1
// baseline (393.135 us; speedup 1.0000x reference)
//
#include <hip/hip_runtime.h>
#include <cstdint>

#define BATCH 512
#define SEQ 256
#define EMB 384
#define HD 64

typedef __attribute__((ext_vector_type(8))) short bf16x8;
typedef __attribute__((ext_vector_type(4))) float f32x4;
typedef __attribute__((ext_vector_type(4))) _Float16 f16x4;

// float -> bf16 round-to-nearest-even (bit trick; inputs are sane, no NaN handling)
static __device__ __forceinline__ short f2bf(float f) {
  uint32_t u = __builtin_bit_cast(uint32_t, f);
  u += 0x7fffu + ((u >> 16) & 1u);
  return (short)(u >> 16);
}

// Prologue: Wt[mat][n][e] = bf16(W_mat[e][n]); mat 0=Wk, 1=Wq (pre-scaled by 1/8), 2=Wv
__global__ void wt_kernel(const float* __restrict__ Wk, const float* __restrict__ Wq,
                          const float* __restrict__ Wv, unsigned short* __restrict__ wt) {
  int idx = blockIdx.x * 256 + threadIdx.x;
  if (idx >= 3 * 64 * 384) return;
  int mat = idx / (64 * 384);
  int rem = idx - mat * (64 * 384);
  int n = rem / 384;
  int e = rem - n * 384;
  const float* W = (mat == 0) ? Wk : ((mat == 1) ? Wq : Wv);
  float v = W[e * 64 + n];
  if (mat == 1) v *= 0.125f;  // fold softmax scale D^-0.5 = 1/8 into Wq
  wt[idx] = (unsigned short)f2bf(v);
}

// LDS map (64 KB total, one 1024-thread block per batch element):
//   K/Q region (aliased in time): element (row,d) at ushort offset
//       row*64 + (((d>>3) ^ (row&7))<<3) + (d&7)          // 16B-granule XOR swizzle
//   Vt region: element (d,key) at ushort offset
//       16384 + d*256 + ((((key>>2)) ^ (d&15))<<2) + (key&3)  // 8B-granule XOR swizzle
__global__ __launch_bounds__(1024) void attn_kernel(const float* __restrict__ X,
                                                    const unsigned short* __restrict__ Wt,
                                                    float* __restrict__ Out) {
  __shared__ unsigned short lds[32768];  // 64 KB
  const int tid  = threadIdx.x;
  const int w    = tid >> 6;   // wave 0..15
  const int lane = tid & 63;
  const int quad = lane >> 4;  // 0..3
  const int l16  = lane & 15;
  const int b    = blockIdx.x;

  // ---------------- Phase 1: fused QKV projection (one pass over X) ----------------
  // Wave w computes rows [16w, 16w+16) of K(0), Q(1), V(2).
  f32x4 acc[3][4];
#pragma unroll
  for (int m = 0; m < 3; ++m)
#pragma unroll
    for (int nt = 0; nt < 4; ++nt) acc[m][nt] = (f32x4){0.f, 0.f, 0.f, 0.f};

  const float* xrow = X + ((size_t)b * SEQ + (size_t)(16 * w + l16)) * EMB;
  for (int ks = 0; ks < 12; ++ks) {
    const int e0 = ks * 32 + quad * 8;
    const f32x4* xp = (const f32x4*)(xrow + e0);
    f32x4 x0 = xp[0];
    f32x4 x1 = xp[1];
    bf16x8 a;
    a[0] = f2bf(x0[0]); a[1] = f2bf(x0[1]); a[2] = f2bf(x0[2]); a[3] = f2bf(x0[3]);
    a[4] = f2bf(x1[0]); a[5] = f2bf(x1[1]); a[6] = f2bf(x1[2]); a[7] = f2bf(x1[3]);
#pragma unroll
    for (int m = 0; m < 3; ++m) {
#pragma unroll
      for (int nt = 0; nt < 4; ++nt) {
        const bf16x8 bfrag = *(const bf16x8*)(Wt + ((m * 64 + nt * 16 + l16) * 384 + e0));
        acc[m][nt] = __builtin_amdgcn_mfma_f32_16x16x32_bf16(a, bfrag, acc[m][nt], 0, 0, 0);
      }
    }
  }

  // ---- Stage Q (C/D layout) into K region of LDS, read back as A-layout fragments ----
#pragma unroll
  for (int nt = 0; nt < 4; ++nt) {
    const int d = nt * 16 + l16;
#pragma unroll
    for (int r = 0; r < 4; ++r) {
      const int row = 16 * w + quad * 4 + r;
      lds[row * 64 + (((d >> 3) ^ (row & 7)) << 3) + (d & 7)] = (unsigned short)f2bf(acc[1][nt][r]);
    }
  }
  __syncthreads();
  bf16x8 qf[2];
  {
    const int row = 16 * w + l16;
    const int sw = row & 7;
#pragma unroll
    for (int kk = 0; kk < 2; ++kk) {
      const int c = kk * 4 + quad;
      qf[kk] = *(const bf16x8*)(lds + row * 64 + ((c ^ sw) << 3));
    }
  }
  __syncthreads();

  // ---- Write K (overwriting Q region) and Vt (as f16) ----
#pragma unroll
  for (int nt = 0; nt < 4; ++nt) {
    const int d = nt * 16 + l16;
#pragma unroll
    for (int r = 0; r < 4; ++r) {
      const int row = 16 * w + quad * 4 + r;
      lds[row * 64 + (((d >> 3) ^ (row & 7)) << 3) + (d & 7)] = (unsigned short)f2bf(acc[0][nt][r]);
    }
    f16x4 hv;
    hv[0] = (_Float16)acc[2][nt][0];
    hv[1] = (_Float16)acc[2][nt][1];
    hv[2] = (_Float16)acc[2][nt][2];
    hv[3] = (_Float16)acc[2][nt][3];
    const int keyb = 16 * w + quad * 4;
    *(f16x4*)(lds + 16384 + d * 256 + (((keyb >> 2) ^ (d & 15)) << 2)) = hv;
  }
  __syncthreads();

  // ---------------- Phase 2: causal flash attention; wave w owns q-tile T=w ----------------
  const int T = w;
  f32x4 o[4];
#pragma unroll
  for (int nt = 0; nt < 4; ++nt) o[nt] = (f32x4){0.f, 0.f, 0.f, 0.f};
  float m_run = -INFINITY;
  float l_run = 0.f;

  for (int j = 0; j <= T; ++j) {
    // S^T = K * Q^T : A = K rows (key = 16j + l16), B = Q rows.
    const int krow = 16 * j + l16;
    const int ksw = krow & 7;
    bf16x8 kf0 = *(const bf16x8*)(lds + krow * 64 + ((quad ^ ksw) << 3));
    bf16x8 kf1 = *(const bf16x8*)(lds + krow * 64 + (((4 + quad) ^ ksw) << 3));
    f32x4 s = {0.f, 0.f, 0.f, 0.f};
    s = __builtin_amdgcn_mfma_f32_16x16x32_bf16(kf0, qf[0], s, 0, 0, 0);
    s = __builtin_amdgcn_mfma_f32_16x16x32_bf16(kf1, qf[1], s, 0, 0, 0);
    // lane holds S[q = 16T+l16][key = 16j + quad*4 + r]
    if (j == T) {
#pragma unroll
      for (int r = 0; r < 4; ++r)
        if (quad * 4 + r > l16) s[r] = -INFINITY;
    }
    // online softmax; row stats live at q = l16, replicated across quads
    float mx = fmaxf(fmaxf(s[0], s[1]), fmaxf(s[2], s[3]));
    mx = fmaxf(mx, __shfl_xor(mx, 16, 64));
    mx = fmaxf(mx, __shfl_xor(mx, 32, 64));
    const float m_new = fmaxf(m_run, mx);
    const float alpha = __expf(m_run - m_new);  // first iter: exp(-inf)=0
    float p0 = __expf(s[0] - m_new);
    float p1 = __expf(s[1] - m_new);
    float p2 = __expf(s[2] - m_new);
    float p3 = __expf(s[3] - m_new);
    float ps = (p0 + p1) + (p2 + p3);
    ps += __shfl_xor(ps, 16, 64);
    ps += __shfl_xor(ps, 32, 64);
    l_run = l_run * alpha + ps;
    m_run = m_new;
    // P tile is already in mfma_16x16x16 A-operand layout: A[m=l16][k=quad*4+r]
    f16x4 pf;
    pf[0] = (_Float16)p0; pf[1] = (_Float16)p1; pf[2] = (_Float16)p2; pf[3] = (_Float16)p3;
    // rescale O (O rows are q = 16T + quad*4 + r -> fetch alpha from lane quad*4+r)
    float al[4];
#pragma unroll
    for (int r = 0; r < 4; ++r) al[r] = __shfl(alpha, quad * 4 + r, 64);
#pragma unroll
    for (int nt = 0; nt < 4; ++nt) {
      o[nt][0] *= al[0]; o[nt][1] *= al[1]; o[nt][2] *= al[2]; o[nt][3] *= al[3];
    }
#pragma unroll
    for (int nt = 0; nt < 4; ++nt) {
      const int d = nt * 16 + l16;
      const f16x4 vf = *(const f16x4*)(lds + 16384 + d * 256 + ((((4 * j + quad)) ^ (d & 15)) << 2));
      o[nt] = __builtin_amdgcn_mfma_f32_16x16x16f16(pf, vf, o[nt], 0, 0, 0);
    }
  }

  // epilogue: normalize rows and store fp32
  const float linv = 1.0f / l_run;
  float li[4];
#pragma unroll
  for (int r = 0; r < 4; ++r) li[r] = __shfl(linv, quad * 4 + r, 64);
  float* op = Out + ((size_t)b * SEQ + 16 * T + quad * 4) * HD + l16;
#pragma unroll
  for (int r = 0; r < 4; ++r) {
#pragma unroll
    for (int nt = 0; nt < 4; ++nt) {
      op[r * HD + nt * 16] = o[nt][r] * li[r];
    }
  }
}

extern "C" void kernel_launch(void* const* d_in, const int* in_sizes, int n_in,
                              void* d_out, int out_size, void* d_ws, size_t ws_size,
                              hipStream_t stream) {
  const float* X  = (const float*)d_in[0];
  const float* Wk = (const float*)d_in[1];
  const float* Wq = (const float*)d_in[2];
  const float* Wv = (const float*)d_in[3];
  unsigned short* wt = (unsigned short*)d_ws;  // 3*64*384*2 = 147456 B of scratch
  float* Out = (float*)d_out;

  wt_kernel<<<dim3(288), dim3(256), 0, stream>>>(Wk, Wq, Wv, wt);
  attn_kernel<<<dim3(BATCH), dim3(1024), 0, stream>>>(X, wt, Out);
}

// Round 2
// 304.571 us; speedup vs baseline: 1.2908x; 1.2908x over previous
//
#include <hip/hip_runtime.h>
#include <cstdint>

#define BATCH 512
#define SEQ 256
#define EMB 384
#define HD 64

typedef __attribute__((ext_vector_type(8))) short bf16x8;
typedef __attribute__((ext_vector_type(4))) float f32x4;
typedef __attribute__((ext_vector_type(4))) _Float16 f16x4;

// float -> bf16 round-to-nearest-even (bit trick; inputs are sane, no NaN handling)
static __device__ __forceinline__ short f2bf(float f) {
  uint32_t u = __builtin_bit_cast(uint32_t, f);
  u += 0x7fffu + ((u >> 16) & 1u);
  return (short)(u >> 16);
}

// Prologue: pre-arrange W^T (bf16, Wq pre-scaled by 1/8) into exact MFMA B-fragment
// order: wt2 flat ushort index = ((ks*12 + m*4 + nt)*64 + lane)*8 + j
//   where n = nt*16 + (lane&15), e = ks*32 + (lane>>4)*8 + j, mat m: 0=Wk,1=Wq,2=Wv.
// This makes per-ks staging one contiguous 12 KB chunk and fragment reads lane*16B.
__global__ void wt_kernel(const float* __restrict__ Wk, const float* __restrict__ Wq,
                          const float* __restrict__ Wv, unsigned short* __restrict__ wt2) {
  int idx = blockIdx.x * 256 + threadIdx.x;
  if (idx >= 12 * 12 * 64 * 8) return;
  int j = idx & 7;
  int lane = (idx >> 3) & 63;
  int grp = idx >> 9;          // 0..143
  int nt = grp & 3;
  int m = (grp >> 2) % 3;
  int ks = grp / 12;
  int n = nt * 16 + (lane & 15);
  int e = ks * 32 + ((lane >> 4) << 3) + j;
  const float* W = (m == 0) ? Wk : ((m == 1) ? Wq : Wv);
  float v = W[e * 64 + n];
  if (m == 1) v *= 0.125f;  // fold softmax scale D^-0.5 = 1/8 into Wq
  wt2[idx] = (unsigned short)f2bf(v);
}

// LDS map (64 KB total, one 1024-thread block per batch element):
//   Phase 1: W double-buffers at ushort offsets [0,6144) and [6144,12288).
//   Phase 1b/2: K/Q region (aliased in time): element (row,d) at ushort offset
//       row*64 + (((d>>3) ^ (row&7))<<3) + (d&7)             // 16B-granule XOR swizzle
//   Vt region: element (d,key) at ushort offset
//       16384 + d*256 + (((key>>2) ^ (d&15))<<2) + (key&3)   // 8B-granule XOR swizzle
__global__ __launch_bounds__(1024) void attn_kernel(const float* __restrict__ X,
                                                    const unsigned short* __restrict__ Wt2,
                                                    float* __restrict__ Out) {
  __shared__ unsigned short lds[32768];  // 64 KB
  const int tid  = threadIdx.x;
  const int w    = tid >> 6;   // wave 0..15
  const int lane = tid & 63;
  const int quad = lane >> 4;  // 0..3
  const int l16  = lane & 15;
  const int b    = blockIdx.x;

  // ---------------- Phase 1: fused QKV projection (one pass over X) ----------------
  // Wave w computes rows [16w, 16w+16) of K(0), Q(1), V(2).
  f32x4 acc[3][4];
#pragma unroll
  for (int m = 0; m < 3; ++m)
#pragma unroll
    for (int nt = 0; nt < 4; ++nt) acc[m][nt] = (f32x4){0.f, 0.f, 0.f, 0.f};

  const float* xrow = X + ((size_t)b * SEQ + (size_t)(16 * w + l16)) * EMB;
  const bool s_act = tid < 768;  // 768 threads x 16B = 12 KB per k-step staging

  // stage ks=0 into buf0; prefetch X k-step 0
  uint4 wreg;
  if (s_act) wreg = *(const uint4*)(Wt2 + (size_t)tid * 8);
  f32x4 xc0 = *(const f32x4*)(xrow + quad * 8);
  f32x4 xc1 = *(const f32x4*)(xrow + quad * 8 + 4);
  if (s_act) *(uint4*)(&lds[tid * 8]) = wreg;
  __syncthreads();

  for (int ks = 0; ks < 12; ++ks) {
    const int cur = ks & 1;
    // issue next W staging load FIRST (so the ds_write's vmcnt wait doesn't drain X prefetch)
    if (ks < 11 && s_act)
      wreg = *(const uint4*)(Wt2 + ((size_t)(ks + 1) * 6144 + (size_t)tid * 8));
    // prefetch next X k-step into registers
    f32x4 xn0, xn1;
    if (ks < 11) {
      const float* xp = xrow + (ks + 1) * 32 + quad * 8;
      xn0 = *(const f32x4*)xp;
      xn1 = *(const f32x4*)(xp + 4);
    }
    // convert current X to bf16 A-fragment
    bf16x8 a;
    a[0] = f2bf(xc0[0]); a[1] = f2bf(xc0[1]); a[2] = f2bf(xc0[2]); a[3] = f2bf(xc0[3]);
    a[4] = f2bf(xc1[0]); a[5] = f2bf(xc1[1]); a[6] = f2bf(xc1[2]); a[7] = f2bf(xc1[3]);
    // 12 MFMAs with W fragments from LDS (conflict-free ds_read_b128 at lane*16)
    const int fb = cur * 6144 + lane * 8;
#pragma unroll
    for (int m = 0; m < 3; ++m) {
#pragma unroll
      for (int nt = 0; nt < 4; ++nt) {
        const bf16x8 bfrag = *(const bf16x8*)(&lds[fb + (m * 4 + nt) * 512]);
        acc[m][nt] = __builtin_amdgcn_mfma_f32_16x16x32_bf16(a, bfrag, acc[m][nt], 0, 0, 0);
      }
    }
    // write next W buffer (vmcnt wait for wreg lands here, after the compute)
    if (ks < 11) {
      if (s_act) *(uint4*)(&lds[(cur ^ 1) * 6144 + tid * 8]) = wreg;
      xc0 = xn0; xc1 = xn1;
      __syncthreads();
    }
  }
  __syncthreads();  // last MFMA's W reads done before Q overwrites the W region

  // ---- Stage Q (C/D layout) into K region of LDS, read back as A-layout fragments ----
#pragma unroll
  for (int nt = 0; nt < 4; ++nt) {
    const int d = nt * 16 + l16;
#pragma unroll
    for (int r = 0; r < 4; ++r) {
      const int row = 16 * w + quad * 4 + r;
      lds[row * 64 + (((d >> 3) ^ (row & 7)) << 3) + (d & 7)] = (unsigned short)f2bf(acc[1][nt][r]);
    }
  }
  __syncthreads();
  bf16x8 qf[2];
  {
    const int row = 16 * w + l16;
    const int sw = row & 7;
#pragma unroll
    for (int kk = 0; kk < 2; ++kk) {
      const int c = kk * 4 + quad;
      qf[kk] = *(const bf16x8*)(lds + row * 64 + ((c ^ sw) << 3));
    }
  }
  __syncthreads();

  // ---- Write K (overwriting Q region) and Vt (as f16) ----
#pragma unroll
  for (int nt = 0; nt < 4; ++nt) {
    const int d = nt * 16 + l16;
#pragma unroll
    for (int r = 0; r < 4; ++r) {
      const int row = 16 * w + quad * 4 + r;
      lds[row * 64 + (((d >> 3) ^ (row & 7)) << 3) + (d & 7)] = (unsigned short)f2bf(acc[0][nt][r]);
    }
    f16x4 hv;
    hv[0] = (_Float16)acc[2][nt][0];
    hv[1] = (_Float16)acc[2][nt][1];
    hv[2] = (_Float16)acc[2][nt][2];
    hv[3] = (_Float16)acc[2][nt][3];
    const int keyb = 16 * w + quad * 4;
    *(f16x4*)(lds + 16384 + d * 256 + (((keyb >> 2) ^ (d & 15)) << 2)) = hv;
  }
  __syncthreads();

  // ---------------- Phase 2: causal flash attention; wave w owns q-tile T=w ----------------
  const int T = w;
  f32x4 o[4];
#pragma unroll
  for (int nt = 0; nt < 4; ++nt) o[nt] = (f32x4){0.f, 0.f, 0.f, 0.f};
  float m_run = -INFINITY;
  float l_run = 0.f;

  for (int j = 0; j <= T; ++j) {
    // S^T = K * Q^T : A = K rows (key = 16j + l16), B = Q rows.
    const int krow = 16 * j + l16;
    const int ksw = krow & 7;
    bf16x8 kf0 = *(const bf16x8*)(lds + krow * 64 + ((quad ^ ksw) << 3));
    bf16x8 kf1 = *(const bf16x8*)(lds + krow * 64 + (((4 + quad) ^ ksw) << 3));
    f32x4 s = {0.f, 0.f, 0.f, 0.f};
    s = __builtin_amdgcn_mfma_f32_16x16x32_bf16(kf0, qf[0], s, 0, 0, 0);
    s = __builtin_amdgcn_mfma_f32_16x16x32_bf16(kf1, qf[1], s, 0, 0, 0);
    // lane holds S[q = 16T+l16][key = 16j + quad*4 + r]
    if (j == T) {
#pragma unroll
      for (int r = 0; r < 4; ++r)
        if (quad * 4 + r > l16) s[r] = -INFINITY;
    }
    // online softmax; row stats live at q = l16, replicated across quads
    float mx = fmaxf(fmaxf(s[0], s[1]), fmaxf(s[2], s[3]));
    mx = fmaxf(mx, __shfl_xor(mx, 16, 64));
    mx = fmaxf(mx, __shfl_xor(mx, 32, 64));
    const float m_new = fmaxf(m_run, mx);
    const float alpha = __expf(m_run - m_new);  // first iter: exp(-inf)=0
    float p0 = __expf(s[0] - m_new);
    float p1 = __expf(s[1] - m_new);
    float p2 = __expf(s[2] - m_new);
    float p3 = __expf(s[3] - m_new);
    float ps = (p0 + p1) + (p2 + p3);
    ps += __shfl_xor(ps, 16, 64);
    ps += __shfl_xor(ps, 32, 64);
    l_run = l_run * alpha + ps;
    m_run = m_new;
    // P tile is already in mfma_16x16x16 A-operand layout: A[m=l16][k=quad*4+r]
    f16x4 pf;
    pf[0] = (_Float16)p0; pf[1] = (_Float16)p1; pf[2] = (_Float16)p2; pf[3] = (_Float16)p3;
    // rescale O (O rows are q = 16T + quad*4 + r -> fetch alpha from lane quad*4+r)
    float al[4];
#pragma unroll
    for (int r = 0; r < 4; ++r) al[r] = __shfl(alpha, quad * 4 + r, 64);
#pragma unroll
    for (int nt = 0; nt < 4; ++nt) {
      o[nt][0] *= al[0]; o[nt][1] *= al[1]; o[nt][2] *= al[2]; o[nt][3] *= al[3];
    }
#pragma unroll
    for (int nt = 0; nt < 4; ++nt) {
      const int d = nt * 16 + l16;
      const f16x4 vf = *(const f16x4*)(lds + 16384 + d * 256 + ((((4 * j + quad)) ^ (d & 15)) << 2));
      o[nt] = __builtin_amdgcn_mfma_f32_16x16x16f16(pf, vf, o[nt], 0, 0, 0);
    }
  }

  // epilogue: normalize rows and store fp32
  const float linv = 1.0f / l_run;
  float li[4];
#pragma unroll
  for (int r = 0; r < 4; ++r) li[r] = __shfl(linv, quad * 4 + r, 64);
  float* op = Out + ((size_t)b * SEQ + 16 * T + quad * 4) * HD + l16;
#pragma unroll
  for (int r = 0; r < 4; ++r) {
#pragma unroll
    for (int nt = 0; nt < 4; ++nt) {
      op[r * HD + nt * 16] = o[nt][r] * li[r];
    }
  }
}

extern "C" void kernel_launch(void* const* d_in, const int* in_sizes, int n_in,
                              void* d_out, int out_size, void* d_ws, size_t ws_size,
                              hipStream_t stream) {
  const float* X  = (const float*)d_in[0];
  const float* Wk = (const float*)d_in[1];
  const float* Wq = (const float*)d_in[2];
  const float* Wv = (const float*)d_in[3];
  unsigned short* wt2 = (unsigned short*)d_ws;  // 3*64*384*2 = 147456 B of scratch
  float* Out = (float*)d_out;

  wt_kernel<<<dim3(288), dim3(256), 0, stream>>>(Wk, Wq, Wv, wt2);
  attn_kernel<<<dim3(BATCH), dim3(1024), 0, stream>>>(X, wt2, Out);
}